// Round 16
// baseline (96.020 us; speedup 1.0000x reference)
//
#include <hip/hip_runtime.h>

// ContinuityLoss: loss = 0.01/(n(n-1)) * sum_{i!=j} exp(-|pi-pj|^2/2) * |oi-oj|
// points: [N,2] f32, outputs: [N,8] f32, scalar f32 out. N = 8192.
//
// R15 = R14 fused into ONE kernel (last-block-done reduction).
// Evidence: R11/R12/R14 all converge to 26-28us despite 4x differences in
// per-wave work and TLP -> shared fixed cost. The two-kernel pipeline
// (1-block cont_final serialized after the tail + second graph launch) is
// the common overhead. Fusion removes it and overlaps the reduce with the
// grid tail. Device-scope pattern per G16: write partial -> __threadfence
// -> atomicAdd(counter, agent scope); last block acquire-fences and reduces
// partials via atomic-relaxed agent loads (defeats stale L1 across XCDs).
// Counter zeroed per call via hipMemsetAsync on stream (graph-capturable;
// atomic order only selects WHO reduces - result is deterministic).
// Math (verified absmax 0.0 since R12): norm-augmented 16x16x16 f16 MFMA;
//   A_O=[o_i,|o_i|^2,1,..], B_O=[-2o_j,1,|o_j|^2,..] -> |oi-oj|^2 complete
//   A_P=[p_i,KE*pn_i,1,0], B_P=[M2*p_j,1,KE*pn_j,0] -> finished exp2 arg
// Epilogue per pair: fmax,sqrt,exp2,fma. Triangular tile grid, diag masks
// j>i, x2 folded into final scale.

typedef float v2f __attribute__((ext_vector_type(2)));
typedef float v4f __attribute__((ext_vector_type(4)));
typedef _Float16 h4 __attribute__((ext_vector_type(4)));
typedef float f32x4 __attribute__((ext_vector_type(4)));

constexpr int N_PTS  = 8192;
constexpr int TDIM   = N_PTS / 64;                // 128 tiles per side
constexpr int NTILES = TDIM * (TDIM + 1) / 2;     // 8256
constexpr int WPB    = 4;                         // waves per block
constexpr int NBLOCKS = NTILES / WPB;             // 2064

constexpr float KE = -0.72134752044448169f;  // -0.5*log2(e)
constexpr float M2 =  1.4426950408889634f;   // -2*KE = log2(e)

__device__ __forceinline__ int tri_before(int r) {
    return r * TDIM - (r * (r - 1)) / 2;
}

__global__ __launch_bounds__(256, 4) void cont_fused(
    const float* __restrict__ points, const float* __restrict__ outputs,
    float* __restrict__ out, double* __restrict__ partials,
    unsigned int* __restrict__ counter, double scale)
{
    const int tid  = threadIdx.x;
    const int wid  = tid >> 6;
    const int lane = tid & 63;
    const int g    = blockIdx.x * WPB + wid;     // global tile id, 0..8255

    // closed-form upper-tri decode + exact integer fixup
    int ti = (int)((2 * TDIM + 1 -
                    sqrtf((float)((2 * TDIM + 1) * (2 * TDIM + 1) - 8 * g))) * 0.5f);
    ti = ti < 0 ? 0 : (ti > TDIM - 1 ? TDIM - 1 : ti);
    while (tri_before(ti + 1) <= g) ++ti;
    while (tri_before(ti) > g) --ti;
    const int tj = ti + (g - tri_before(ti));
    const bool diag = (ti == tj);

    const int q = lane >> 4, cl = lane & 15;
    const int rowbase = ti * 64, colbase = tj * 64;

    const _Float16 h0 = (_Float16)0.f, h1 = (_Float16)1.f;

    // i-side fragments (A operands), norm-augmented
    h4 aO[4], aP[4];
    #pragma unroll
    for (int it = 0; it < 4; ++it) {
        const int i = rowbase + it * 16 + cl;
        const v4f* o = reinterpret_cast<const v4f*>(outputs + 8 * i);
        const v4f x = o[0], y = o[1];
        const v4f s = x * x + y * y;
        const float on = (s.x + s.y) + (s.z + s.w);
        const v2f p = reinterpret_cast<const v2f*>(points)[i];
        const float pn = p.x * p.x + p.y * p.y;
        h4 a;
        if (q == 0)      a = h4{(_Float16)x.x, (_Float16)x.y, (_Float16)x.z, (_Float16)x.w};
        else if (q == 1) a = h4{(_Float16)y.x, (_Float16)y.y, (_Float16)y.z, (_Float16)y.w};
        else if (q == 2) a = h4{(_Float16)on, h1, h0, h0};
        else             a = h4{h0, h0, h0, h0};
        aO[it] = a;
        if (q == 0) aP[it] = h4{(_Float16)p.x, (_Float16)p.y, (_Float16)(KE * pn), h1};
        else        aP[it] = h4{h0, h0, h0, h0};
    }

    float accE[4] = {0.f, 0.f, 0.f, 0.f};

    // prefetched j-side raw data for jt=0
    v4f jx, jy; v2f jp;
    {
        const int j = colbase + cl;
        const v4f* o = reinterpret_cast<const v4f*>(outputs + 8 * j);
        jx = o[0]; jy = o[1];
        jp = reinterpret_cast<const v2f*>(points)[j];
    }

    #pragma unroll
    for (int jt = 0; jt < 4; ++jt) {
        const v4f s = jx * jx + jy * jy;
        const float on = (s.x + s.y) + (s.z + s.w);
        const float pn = jp.x * jp.x + jp.y * jp.y;
        h4 bO, bP;
        if (q == 0)      bO = h4{(_Float16)(-2.f * jx.x), (_Float16)(-2.f * jx.y),
                                 (_Float16)(-2.f * jx.z), (_Float16)(-2.f * jx.w)};
        else if (q == 1) bO = h4{(_Float16)(-2.f * jy.x), (_Float16)(-2.f * jy.y),
                                 (_Float16)(-2.f * jy.z), (_Float16)(-2.f * jy.w)};
        else if (q == 2) bO = h4{h1, (_Float16)on, h0, h0};
        else             bO = h4{h0, h0, h0, h0};
        if (q == 0) bP = h4{(_Float16)(M2 * jp.x), (_Float16)(M2 * jp.y), h1,
                            (_Float16)(KE * pn)};
        else        bP = h4{h0, h0, h0, h0};
        const int jcol = jt * 16 + cl;           // C/D col of this lane

        if (jt < 3) {
            const int jn = colbase + (jt + 1) * 16 + cl;
            const v4f* o = reinterpret_cast<const v4f*>(outputs + 8 * jn);
            jx = o[0]; jy = o[1];
            jp = reinterpret_cast<const v2f*>(points)[jn];
        }

        #pragma unroll
        for (int it = 0; it < 4; ++it) {
            const f32x4 z = {0.f, 0.f, 0.f, 0.f};
            f32x4 dO = __builtin_amdgcn_mfma_f32_16x16x16f16(aO[it], bO, z, 0, 0, 0);
            f32x4 dP = __builtin_amdgcn_mfma_f32_16x16x16f16(aP[it], bP, z, 0, 0, 0);
            #pragma unroll
            for (int e = 0; e < 4; ++e) {
                float diff = __builtin_amdgcn_sqrtf(fmaxf(dO[e], 0.f));
                if (diag) {
                    const int irow = it * 16 + q * 4 + e;   // C/D row
                    diff = (jcol > irow) ? diff : 0.f;
                }
                accE[e] = fmaf(__builtin_amdgcn_exp2f(dP[e]), diff, accE[e]);
            }
        }
    }

    float accS = (accE[0] + accE[1]) + (accE[2] + accE[3]);
    #pragma unroll
    for (int off = 32; off > 0; off >>= 1)
        accS += __shfl_down(accS, off, 64);

    __shared__ float wpart[WPB];
    __shared__ int s_last;
    if (lane == 0) wpart[wid] = accS;
    __syncthreads();

    if (tid == 0) {
        double d = 0.0;
        #pragma unroll
        for (int w = 0; w < WPB; ++w) d += (double)wpart[w];
        partials[blockIdx.x] = d;
        __threadfence();                         // release (device scope)
        unsigned int done = __hip_atomic_fetch_add(
            counter, 1u, __ATOMIC_ACQ_REL, __HIP_MEMORY_SCOPE_AGENT);
        s_last = (done == (unsigned int)(NBLOCKS - 1)) ? 1 : 0;
    }
    __syncthreads();

    if (s_last) {
        __threadfence();                         // acquire
        double sum = 0.0;
        for (int i = tid; i < NBLOCKS; i += 256)
            sum += __hip_atomic_load(&partials[i], __ATOMIC_RELAXED,
                                     __HIP_MEMORY_SCOPE_AGENT);
        #pragma unroll
        for (int off = 32; off > 0; off >>= 1)
            sum += __shfl_down(sum, off, 64);
        __shared__ double ws[4];
        if ((tid & 63) == 0) ws[tid >> 6] = sum;
        __syncthreads();
        if (tid == 0) {
            double t = (ws[0] + ws[1]) + (ws[2] + ws[3]);
            out[0] = (float)(t * scale);
        }
    }
}

extern "C" void kernel_launch(void* const* d_in, const int* in_sizes, int n_in,
                              void* d_out, int out_size, void* d_ws, size_t ws_size,
                              hipStream_t stream) {
    const float* points  = (const float*)d_in[0];
    const float* outputs = (const float*)d_in[1];
    float* out = (float*)d_out;

    const int n = in_sizes[0] / 2;                       // 8192
    unsigned int* counter = (unsigned int*)d_ws;         // 4B @ offset 0
    double* partials = (double*)((char*)d_ws + 256);     // 2064 * 8B

    hipMemsetAsync(d_ws, 0, 256, stream);                // zero the counter

    // each unordered pair counted once -> weight 2 folded into the scale
    const double scale = 0.01 * 2.0 / ((double)n * (double)(n - 1));
    cont_fused<<<dim3(NBLOCKS), dim3(256), 0, stream>>>(
        points, outputs, out, partials, counter, scale);
}

// Round 18
// 23.110 us; speedup vs baseline: 4.1549x; 4.1549x over previous
//
#include <hip/hip_runtime.h>

// ContinuityLoss: loss = 0.01/(n(n-1)) * sum_{i!=j} exp(-|pi-pj|^2/2) * |oi-oj|
// points: [N,2] f32, outputs: [N,8] f32, scalar f32 out. N = 8192.
//
// R16 (resubmitted R17 after infra failure): hoist MFMA fragment
// construction out of the O(N^2) loop.
// R15's visible counters showed ~1780 VALU insts/wave: per-tile f16 cvt +
// norm + (-2)*scale + quad cndmask-select rebuilt each point's fragment
// ~128x across tiles. A prep kernel now builds lane-exact fragment tables
// AO/AP/BO/BP[512 tiles][64 lanes] (h4, 1MB, L2-resident); the pair kernel
// loads its fragments (8B coalesced loads, all hoisted) and runs only
// MFMA + epilogue. Packaging = R14's best (2064 x 4-wave blocks,
// launch_bounds(256,4), separate final-reduce kernel, NO device fences -
// R15 proved last-block fences cost ~60us on split-L2 gfx950).
// Math (verified absmax 0.0 since R12): norm-augmented 16x16x16 f16 MFMA;
//   A_O=[o_i,|o_i|^2,1,..], B_O=[-2o_j,1,|o_j|^2,..] -> |oi-oj|^2 complete
//   A_P=[p_i,KE*pn_i,1,0], B_P=[M2*p_j,1,KE*pn_j,0] -> finished exp2 arg
// Epilogue: fmax,sqrt,exp2,fma. Triangular tile grid, diag masks j>i,
// x2 folded into the final scale.

typedef float v2f __attribute__((ext_vector_type(2)));
typedef float v4f __attribute__((ext_vector_type(4)));
typedef _Float16 h4 __attribute__((ext_vector_type(4)));
typedef float f32x4 __attribute__((ext_vector_type(4)));

constexpr int N_PTS  = 8192;
constexpr int T16    = N_PTS / 16;                // 512 16-row tiles
constexpr int TDIM   = N_PTS / 64;                // 128 64-tiles per side
constexpr int NTILES = TDIM * (TDIM + 1) / 2;     // 8256
constexpr int WPB    = 4;                         // waves per block
constexpr int NBLOCKS = NTILES / WPB;             // 2064

constexpr float KE = -0.72134752044448169f;  // -0.5*log2(e)
constexpr float M2 =  1.4426950408889634f;   // -2*KE = log2(e)

__device__ __forceinline__ int tri_before(int r) {
    return r * TDIM - (r * (r - 1)) / 2;
}

// one thread per (16-tile, lane): emit that lane's A/B fragment words
__global__ __launch_bounds__(256) void cont_prep(
    const float* __restrict__ points, const float* __restrict__ outputs,
    h4* __restrict__ AO, h4* __restrict__ AP,
    h4* __restrict__ BO, h4* __restrict__ BP)
{
    const int idx = blockIdx.x * 256 + threadIdx.x;   // 0..32767
    const int l  = idx & 63;
    const int t  = idx >> 6;
    const int q  = l >> 4, cl = l & 15;
    const int row = t * 16 + cl;

    const v4f* o = reinterpret_cast<const v4f*>(outputs + 8 * row);
    const v4f x = o[0], y = o[1];
    const v4f s = x * x + y * y;
    const float on = (s.x + s.y) + (s.z + s.w);
    const v2f p = reinterpret_cast<const v2f*>(points)[row];
    const float pn = p.x * p.x + p.y * p.y;

    const _Float16 h0 = (_Float16)0.f, h1 = (_Float16)1.f;
    h4 ao, ap, bo, bp;
    if (q == 0)      ao = h4{(_Float16)x.x, (_Float16)x.y, (_Float16)x.z, (_Float16)x.w};
    else if (q == 1) ao = h4{(_Float16)y.x, (_Float16)y.y, (_Float16)y.z, (_Float16)y.w};
    else if (q == 2) ao = h4{(_Float16)on, h1, h0, h0};
    else             ao = h4{h0, h0, h0, h0};
    if (q == 0) ap = h4{(_Float16)p.x, (_Float16)p.y, (_Float16)(KE * pn), h1};
    else        ap = h4{h0, h0, h0, h0};
    if (q == 0)      bo = h4{(_Float16)(-2.f * x.x), (_Float16)(-2.f * x.y),
                             (_Float16)(-2.f * x.z), (_Float16)(-2.f * x.w)};
    else if (q == 1) bo = h4{(_Float16)(-2.f * y.x), (_Float16)(-2.f * y.y),
                             (_Float16)(-2.f * y.z), (_Float16)(-2.f * y.w)};
    else if (q == 2) bo = h4{h1, (_Float16)on, h0, h0};
    else             bo = h4{h0, h0, h0, h0};
    if (q == 0) bp = h4{(_Float16)(M2 * p.x), (_Float16)(M2 * p.y), h1,
                        (_Float16)(KE * pn)};
    else        bp = h4{h0, h0, h0, h0};

    AO[idx] = ao; AP[idx] = ap; BO[idx] = bo; BP[idx] = bp;
}

__global__ __launch_bounds__(256, 4) void cont_pairs(
    const h4* __restrict__ AO, const h4* __restrict__ AP,
    const h4* __restrict__ BO, const h4* __restrict__ BP,
    double* __restrict__ partials)
{
    const int tid  = threadIdx.x;
    const int wid  = tid >> 6;
    const int lane = tid & 63;
    const int g    = blockIdx.x * WPB + wid;     // global tile id, 0..8255

    // closed-form upper-tri decode + exact integer fixup
    int ti = (int)((2 * TDIM + 1 -
                    sqrtf((float)((2 * TDIM + 1) * (2 * TDIM + 1) - 8 * g))) * 0.5f);
    ti = ti < 0 ? 0 : (ti > TDIM - 1 ? TDIM - 1 : ti);
    while (tri_before(ti + 1) <= g) ++ti;
    while (tri_before(ti) > g) --ti;
    const int tj = ti + (g - tri_before(ti));
    const bool diag = (ti == tj);

    const int q = lane >> 4, cl = lane & 15;

    // all fragments loaded up front (coalesced 8B lane loads, latency hoisted)
    h4 aO[4], aP[4], bO[4], bP[4];
    #pragma unroll
    for (int it = 0; it < 4; ++it) {
        const int ta = (ti * 4 + it) * 64 + lane;
        aO[it] = AO[ta]; aP[it] = AP[ta];
        const int tb = (tj * 4 + it) * 64 + lane;
        bO[it] = BO[tb]; bP[it] = BP[tb];
    }

    float accE[4] = {0.f, 0.f, 0.f, 0.f};

    #pragma unroll
    for (int jt = 0; jt < 4; ++jt) {
        const int jcol = jt * 16 + cl;           // C/D col of this lane
        #pragma unroll
        for (int it = 0; it < 4; ++it) {
            const f32x4 z = {0.f, 0.f, 0.f, 0.f};
            f32x4 dO = __builtin_amdgcn_mfma_f32_16x16x16f16(aO[it], bO[jt], z, 0, 0, 0);
            f32x4 dP = __builtin_amdgcn_mfma_f32_16x16x16f16(aP[it], bP[jt], z, 0, 0, 0);
            #pragma unroll
            for (int e = 0; e < 4; ++e) {
                float diff = __builtin_amdgcn_sqrtf(fmaxf(dO[e], 0.f));
                if (diag) {
                    const int irow = it * 16 + q * 4 + e;   // C/D row
                    diff = (jcol > irow) ? diff : 0.f;
                }
                accE[e] = fmaf(__builtin_amdgcn_exp2f(dP[e]), diff, accE[e]);
            }
        }
    }

    float accS = (accE[0] + accE[1]) + (accE[2] + accE[3]);
    #pragma unroll
    for (int off = 32; off > 0; off >>= 1)
        accS += __shfl_down(accS, off, 64);

    __shared__ float wpart[WPB];
    if (lane == 0) wpart[wid] = accS;
    __syncthreads();
    if (tid == 0) {
        double d = 0.0;
        #pragma unroll
        for (int w = 0; w < WPB; ++w) d += (double)wpart[w];
        partials[blockIdx.x] = d;
    }
}

__global__ __launch_bounds__(1024) void cont_final(
    const double* __restrict__ partials, int nparts,
    float* __restrict__ out, double scale)
{
    const int tid = threadIdx.x;
    double sum = 0.0;
    for (int i = tid; i < nparts; i += 1024) sum += partials[i];
    #pragma unroll
    for (int off = 32; off > 0; off >>= 1)
        sum += __shfl_down(sum, off, 64);

    __shared__ double ws[1024 / 64];
    if ((tid & 63) == 0) ws[tid >> 6] = sum;
    __syncthreads();
    if (tid == 0) {
        double t = 0.0;
        #pragma unroll
        for (int w = 0; w < 1024 / 64; ++w) t += ws[w];
        out[0] = (float)(t * scale);
    }
}

extern "C" void kernel_launch(void* const* d_in, const int* in_sizes, int n_in,
                              void* d_out, int out_size, void* d_ws, size_t ws_size,
                              hipStream_t stream) {
    const float* points  = (const float*)d_in[0];
    const float* outputs = (const float*)d_in[1];
    float* out = (float*)d_out;

    const int n = in_sizes[0] / 2;               // 8192
    constexpr size_t TBL = (size_t)T16 * 64 * sizeof(h4);   // 256 KB per table
    h4* AO = (h4*)d_ws;
    h4* AP = (h4*)((char*)d_ws + TBL);
    h4* BO = (h4*)((char*)d_ws + 2 * TBL);
    h4* BP = (h4*)((char*)d_ws + 3 * TBL);
    double* partials = (double*)((char*)d_ws + 4 * TBL);    // 2064 * 8B

    cont_prep<<<dim3(T16 * 64 / 256), dim3(256), 0, stream>>>(
        points, outputs, AO, AP, BO, BP);
    cont_pairs<<<dim3(NBLOCKS), dim3(256), 0, stream>>>(AO, AP, BO, BP, partials);

    // each unordered pair counted once -> weight 2 folded into the scale
    const double scale = 0.01 * 2.0 / ((double)n * (double)(n - 1));
    cont_final<<<1, 1024, 0, stream>>>(partials, NBLOCKS, out, scale);
}